// Round 3
// baseline (626.316 us; speedup 1.0000x reference)
//
#include <hip/hip_runtime.h>
#include <hip/hip_bf16.h>

#define NSEQ 512
#define DDIM 128
#define NPOS (NSEQ*NSEQ)

typedef __bf16 bf16x8 __attribute__((ext_vector_type(8)));
typedef float f32x4 __attribute__((ext_vector_type(4)));
typedef unsigned short us4 __attribute__((ext_vector_type(4)));
typedef unsigned int u32x4 __attribute__((ext_vector_type(4)));

__device__ __forceinline__ unsigned short f2bf(float f){
  unsigned int u = __float_as_uint(f);
  u += 0x7fffu + ((u >> 16) & 1u);
  return (unsigned short)(u >> 16);
}
__device__ __forceinline__ float bf2f(unsigned short s){
  return __uint_as_float(((unsigned int)s) << 16);
}
__device__ __forceinline__ float sigmoidf_(float x){
  return 1.0f/(1.0f + __expf(-x));
}

// ---------------- K0: weight prep (transpose to [out_col][k], bf16) ----------
// wt rows: [0..255]=W_lr^T, [256..511]=W_gate^T, [512..639]=W_og^T, [640..767]=W_op^T
__global__ void k_prep(const float* __restrict__ Wlr, const float* __restrict__ Wgate,
                       const float* __restrict__ Wog, const float* __restrict__ Wop,
                       unsigned short* __restrict__ wt)
{
  int idx = blockIdx.x*256 + threadIdx.x;
  if (idx >= 768*128) return;
  int row = idx >> 7, k = idx & 127;
  float v;
  if (row < 256)      v = Wlr[k*256 + row];
  else if (row < 512) v = Wgate[k*256 + (row-256)];
  else if (row < 640) v = Wog[k*128 + (row-512)];
  else                v = Wop[k*128 + (row-640)];
  wt[idx] = f2bf(v);
}

// ---- 32x64 per-wave GEMM over K=128: A from LDS band, B direct from global ----
// acc[fi 0..1][fj 0..3], rows wid*32+fi*16+(lq*4+e), cols fj*16+lr_
__device__ __forceinline__ void gemm64(const unsigned short (&A)[128][136],
                                       const unsigned short* __restrict__ wbase,
                                       int wid, int lr_, int lq, f32x4 (&acc)[2][4])
{
  #pragma unroll
  for (int s = 0; s < 4; ++s){
    const int k0 = s*32 + lq*8;
    bf16x8 a[2], b[4];
    #pragma unroll
    for (int fi = 0; fi < 2; ++fi)
      a[fi] = *reinterpret_cast<const bf16x8*>(&A[wid*32 + fi*16 + lr_][k0]);
    #pragma unroll
    for (int fj = 0; fj < 4; ++fj)
      b[fj] = *reinterpret_cast<const bf16x8*>(wbase + ((fj*16 + lr_) << 7) + k0);
    #pragma unroll
    for (int fi = 0; fi < 2; ++fi)
      #pragma unroll
      for (int fj = 0; fj < 4; ++fj)
        acc[fi][fj] = __builtin_amdgcn_mfma_f32_16x16x32_bf16(a[fi], b[fj], acc[fi][fj], 0, 0, 0);
  }
}

// ---------------- K1: LN1 + (lr,gate,og) GEMMs + gating ---------------------
// 128 positions per block, 4 waves each owning a 32-row band of zln.
// Weights read directly from global (L1/L2-hot) -> no weight LDS, 3 syncs total.
__global__ __launch_bounds__(256, 4)
void k1(const float* __restrict__ Zraw, const float* __restrict__ mask,
        const float* __restrict__ ln1g, const float* __restrict__ ln1b,
        const float* __restrict__ blr, const float* __restrict__ bgate,
        const float* __restrict__ bog,
        const unsigned short* __restrict__ wt,
        unsigned short* __restrict__ left_t, unsigned short* __restrict__ right_t,
        unsigned short* __restrict__ g_ws)
{
  __shared__ unsigned short zln[128][136];

  const int t = threadIdx.x;
  const int posb = blockIdx.x * 128;
  const int r = t >> 1, h = t & 1;
  const int lane = t & 63, wid = t >> 6;
  const int lr_ = lane & 15, lq = lane >> 4;

  // ---- LN1: 2 threads per row; packed b128 LDS writes (bank-optimal) ----
  {
    const float* src = Zraw + (size_t)(posb + r)*DDIM + h*64;
    float v[64];
    float s = 0.f, sq = 0.f;
    #pragma unroll
    for (int i = 0; i < 16; ++i){
      f32x4 x = *reinterpret_cast<const f32x4*>(src + i*4);
      v[i*4+0] = x[0]; v[i*4+1] = x[1]; v[i*4+2] = x[2]; v[i*4+3] = x[3];
    }
    #pragma unroll
    for (int i = 0; i < 64; ++i){ s += v[i]; sq += v[i]*v[i]; }
    s  += __shfl_xor(s, 1);
    sq += __shfl_xor(sq, 1);
    float mu = s * (1.0f/128.0f);
    float var = sq * (1.0f/128.0f) - mu*mu;
    float rs = rsqrtf(var + 1e-5f);
    #pragma unroll
    for (int q = 0; q < 8; ++q){
      u32x4 pk;
      #pragma unroll
      for (int e = 0; e < 4; ++e){
        int c0 = h*64 + q*8 + 2*e;
        float a = (v[q*8+2*e]   - mu)*rs*ln1g[c0]   + ln1b[c0];
        float b = (v[q*8+2*e+1] - mu)*rs*ln1g[c0+1] + ln1b[c0+1];
        pk[e] = (unsigned int)f2bf(a) | ((unsigned int)f2bf(b) << 16);
      }
      *reinterpret_cast<u32x4*>(&zln[r][h*64 + q*8]) = pk;
    }
  }
  __syncthreads();

  // preload mask values for this thread's output rows
  float mpre[2][4];
  #pragma unroll
  for (int fi = 0; fi < 2; ++fi)
    #pragma unroll
    for (int e = 0; e < 4; ++e)
      mpre[fi][e] = mask[posb + wid*32 + fi*16 + lq*4 + e];

  // ---- lr/gate: 2 pairs x 2 halves of 64 cols ----
  #pragma unroll 1
  for (int pair = 0; pair < 2; ++pair){
    unsigned short* dst = pair ? right_t : left_t;
    #pragma unroll 1
    for (int half = 0; half < 2; ++half){
      const int colb = half*64;
      // gate GEMM
      f32x4 ag[2][4];
      #pragma unroll
      for (int a1 = 0; a1 < 2; ++a1)
        #pragma unroll
        for (int a2 = 0; a2 < 4; ++a2) ag[a1][a2] = (f32x4){0.f,0.f,0.f,0.f};
      gemm64(zln, wt + (size_t)(256 + pair*128 + colb)*128, wid, lr_, lq, ag);
      float gs[2][4][4];
      #pragma unroll
      for (int fi = 0; fi < 2; ++fi)
        #pragma unroll
        for (int fj = 0; fj < 4; ++fj){
          float bb = bgate[pair*128 + colb + fj*16 + lr_];
          #pragma unroll
          for (int e = 0; e < 4; ++e)
            gs[fi][fj][e] = sigmoidf_(ag[fi][fj][e] + bb);
        }
      // lr GEMM
      f32x4 al[2][4];
      #pragma unroll
      for (int a1 = 0; a1 < 2; ++a1)
        #pragma unroll
        for (int a2 = 0; a2 < 4; ++a2) al[a1][a2] = (f32x4){0.f,0.f,0.f,0.f};
      gemm64(zln, wt + (size_t)(pair*128 + colb)*128, wid, lr_, lq, al);
      // combine + store to [c][pos]
      #pragma unroll
      for (int fi = 0; fi < 2; ++fi){
        const int rowb = wid*32 + fi*16 + lq*4;
        #pragma unroll
        for (int fj = 0; fj < 4; ++fj){
          const int col = colb + fj*16 + lr_;
          float bb = blr[pair*128 + col];
          us4 o;
          o[0] = f2bf((al[fi][fj][0] + bb) * mpre[fi][0] * gs[fi][fj][0]);
          o[1] = f2bf((al[fi][fj][1] + bb) * mpre[fi][1] * gs[fi][fj][1]);
          o[2] = f2bf((al[fi][fj][2] + bb) * mpre[fi][2] * gs[fi][fj][2]);
          o[3] = f2bf((al[fi][fj][3] + bb) * mpre[fi][3] * gs[fi][fj][3]);
          *reinterpret_cast<us4*>(dst + (size_t)col*NPOS + posb + rowb) = o;
        }
      }
    }
  }

  // ---- og -> g (both halves, then bounce through zln for coalesced store) ----
  f32x4 ao[2][2][4];
  #pragma unroll
  for (int hf = 0; hf < 2; ++hf){
    #pragma unroll
    for (int a1 = 0; a1 < 2; ++a1)
      #pragma unroll
      for (int a2 = 0; a2 < 4; ++a2) ao[hf][a1][a2] = (f32x4){0.f,0.f,0.f,0.f};
    gemm64(zln, wt + (size_t)(512 + hf*64)*128, wid, lr_, lq, ao[hf]);
  }
  __syncthreads();   // all A-reads of zln complete before overwrite
  #pragma unroll
  for (int hf = 0; hf < 2; ++hf)
    #pragma unroll
    for (int fi = 0; fi < 2; ++fi)
      #pragma unroll
      for (int fj = 0; fj < 4; ++fj){
        const int col = hf*64 + fj*16 + lr_;
        float bb = bog[col];
        #pragma unroll
        for (int e = 0; e < 4; ++e)
          zln[wid*32 + fi*16 + lq*4 + e][col] = f2bf(sigmoidf_(ao[hf][fi][fj][e] + bb));
      }
  __syncthreads();
  { // coalesced copy out: g_ws[pos][d]
    unsigned short* dstg = g_ws + (size_t)(posb + r)*DDIM + h*64;
    #pragma unroll
    for (int q = 0; q < 8; ++q)
      *reinterpret_cast<u32x4*>(dstg + q*8) =
          *reinterpret_cast<const u32x4*>(&zln[r][h*64 + q*8]);
  }
}

// ---------------- K2: per-channel NT GEMM p = L * R^T, 256x256 tiles --------
// A-operand = RIGHT rows (j), B-operand = LEFT rows (i) => D[m=j][n=i] = p[i][j].
// 512 threads, 8 waves (2x4), each wave 128x64 output.
__global__ __launch_bounds__(512, 1)
void k2(const unsigned short* __restrict__ left_t,
        const unsigned short* __restrict__ right_t,
        unsigned short* __restrict__ p_ws)
{
  __shared__ unsigned short At[256][72];  // right rows j
  __shared__ unsigned short Bt[256][72];  // left  rows i

  const int t = threadIdx.x;
  const int c = blockIdx.y;
  const int it = blockIdx.x >> 1, jt = blockIdx.x & 1;
  const int i0 = it*256, j0 = jt*256;
  const int lane = t & 63, wid = t >> 6;
  const int wr = wid >> 2, wc = wid & 3;
  const int lr_ = lane & 15, lq = lane >> 4;
  const size_t cbase = (size_t)c * NPOS;
  const int rs_ = t >> 3;              // staging row within 64-row group
  const int cs_ = (t & 7) * 8;         // staging col (shorts)

  f32x4 acc[8][4];
  #pragma unroll
  for (int a1 = 0; a1 < 8; ++a1)
    #pragma unroll
    for (int a2 = 0; a2 < 4; ++a2) acc[a1][a2] = (f32x4){0.f,0.f,0.f,0.f};

  #pragma unroll 1
  for (int kk = 0; kk < 8; ++kk){
    const int k0 = kk*64;
    __syncthreads();
    #pragma unroll
    for (int q = 0; q < 4; ++q){
      const int rr = q*64 + rs_;
      *reinterpret_cast<u32x4*>(&At[rr][cs_]) =
          *reinterpret_cast<const u32x4*>(right_t + cbase + (size_t)(j0+rr)*NSEQ + k0 + cs_);
      *reinterpret_cast<u32x4*>(&Bt[rr][cs_]) =
          *reinterpret_cast<const u32x4*>(left_t  + cbase + (size_t)(i0+rr)*NSEQ + k0 + cs_);
    }
    __syncthreads();
    #pragma unroll
    for (int s = 0; s < 2; ++s){
      const int kl = s*32 + lq*8;
      bf16x8 a[8], b[4];
      #pragma unroll
      for (int f = 0; f < 8; ++f)
        a[f] = *reinterpret_cast<const bf16x8*>(&At[wr*128 + f*16 + lr_][kl]);
      #pragma unroll
      for (int f = 0; f < 4; ++f)
        b[f] = *reinterpret_cast<const bf16x8*>(&Bt[wc*64 + f*16 + lr_][kl]);
      #pragma unroll
      for (int fi = 0; fi < 8; ++fi)
        #pragma unroll
        for (int fj = 0; fj < 4; ++fj)
          acc[fi][fj] = __builtin_amdgcn_mfma_f32_16x16x32_bf16(a[fi], b[fj], acc[fi][fj], 0, 0, 0);
    }
  }

  #pragma unroll
  for (int fi = 0; fi < 8; ++fi){
    const int jr = j0 + wr*128 + fi*16 + lq*4;
    #pragma unroll
    for (int fj = 0; fj < 4; ++fj){
      const int ic = i0 + wc*64 + fj*16 + lr_;
      us4 o;
      o[0] = f2bf(acc[fi][fj][0]);
      o[1] = f2bf(acc[fi][fj][1]);
      o[2] = f2bf(acc[fi][fj][2]);
      o[3] = f2bf(acc[fi][fj][3]);
      *reinterpret_cast<us4*>(p_ws + cbase + (size_t)ic*NSEQ + jr) = o;
    }
  }
}

// K=128 MFMA tile helper for k3 (2x2 wave grid, 64x64 per wave)
__device__ __forceinline__ void mfma_k128(const unsigned short (&A)[128][136],
                                          const unsigned short (&B)[128][136],
                                          int wrow, int wcol, int lr_, int lq,
                                          f32x4 (&acc)[4][4])
{
  #pragma unroll
  for (int s = 0; s < 4; ++s){
    const int k0 = s*32 + lq*8;
    bf16x8 a[4], b[4];
    #pragma unroll
    for (int f = 0; f < 4; ++f)
      a[f] = *reinterpret_cast<const bf16x8*>(&A[wrow*64 + f*16 + lr_][k0]);
    #pragma unroll
    for (int f = 0; f < 4; ++f)
      b[f] = *reinterpret_cast<const bf16x8*>(&B[wcol*64 + f*16 + lr_][k0]);
    #pragma unroll
    for (int fi = 0; fi < 4; ++fi)
      #pragma unroll
      for (int fj = 0; fj < 4; ++fj)
        acc[fi][fj] = __builtin_amdgcn_mfma_f32_16x16x32_bf16(a[fi], b[fj], acc[fi][fj], 0, 0, 0);
  }
}

// ---------------- K3: LN2 + @W_op + gated residual ---------------------------
// Block: one i row, 128 consecutive j. p is [c][i][j]. Single global read of p:
// stats pass stashes raw bf16 into LDS [j][c]; normalize in place; MFMA.
__global__ __launch_bounds__(256, 2)
void k3(const unsigned short* __restrict__ p_ws, const unsigned short* __restrict__ g_ws,
        const float* __restrict__ Zraw,
        const float* __restrict__ ln2g, const float* __restrict__ ln2b,
        const unsigned short* __restrict__ wt, const float* __restrict__ obias,
        float* __restrict__ out)
{
  __shared__ unsigned short pj[128][136];   // [j][c]
  __shared__ unsigned short wop[128][136];  // [d][c]
  __shared__ float part[8][32][8];
  __shared__ float mu_s[128], rs_s[128];

  const int t = threadIdx.x;
  const int i = blockIdx.x >> 2;
  const int j0 = (blockIdx.x & 3) * 128;
  const int r = t >> 1, h = t & 1;

  { // stage W_op^T
    const unsigned short* src = wt + (size_t)(640 + r)*128 + h*64;
    #pragma unroll
    for (int q = 0; q < 8; ++q)
      *reinterpret_cast<u32x4*>(&wop[r][h*64 + q*8]) =
          *reinterpret_cast<const u32x4*>(src + q*8);
  }

  { // phase A: coalesced streaming load -> stats partials + raw stash to pj
    const int j4 = t & 31, grp = t >> 5;
    float s[4] = {0,0,0,0}, sq[4] = {0,0,0,0};
    const unsigned short* base = p_ws + (size_t)i*NSEQ + j0 + j4*4;
    #pragma unroll
    for (int it2 = 0; it2 < 16; ++it2){
      int cc = grp + it2*8;
      us4 v = *reinterpret_cast<const us4*>(base + (size_t)cc*NPOS);
      #pragma unroll
      for (int e = 0; e < 4; ++e){
        float f = bf2f(v[e]);
        s[e] += f; sq[e] += f*f;
        pj[j4*4 + e][cc] = v[e];
      }
    }
    #pragma unroll
    for (int e = 0; e < 4; ++e){ part[grp][j4][e] = s[e]; part[grp][j4][4+e] = sq[e]; }
  }
  __syncthreads();
  if (t < 128){
    float s = 0.f, sq = 0.f;
    #pragma unroll
    for (int g2 = 0; g2 < 8; ++g2){
      s  += part[g2][t>>2][t&3];
      sq += part[g2][t>>2][4 + (t&3)];
    }
    float mu = s*(1.f/128.f);
    float var = sq*(1.f/128.f) - mu*mu;
    mu_s[t] = mu;
    rs_s[t] = rsqrtf(var + 1e-5f);
  }
  __syncthreads();

  { // normalize pj in place (b128 reads/writes, bank-optimal)
    float mu = mu_s[r], rs = rs_s[r];
    #pragma unroll
    for (int q = 0; q < 8; ++q){
      const int c0 = h*64 + q*8;
      u32x4 pk = *reinterpret_cast<const u32x4*>(&pj[r][c0]);
      u32x4 o;
      #pragma unroll
      for (int e = 0; e < 4; ++e){
        const int cc = c0 + 2*e;
        unsigned int w2 = pk[e];
        float a = (bf2f((unsigned short)(w2 & 0xffffu)) - mu)*rs*ln2g[cc]   + ln2b[cc];
        float b = (bf2f((unsigned short)(w2 >> 16))     - mu)*rs*ln2g[cc+1] + ln2b[cc+1];
        o[e] = (unsigned int)f2bf(a) | ((unsigned int)f2bf(b) << 16);
      }
      *reinterpret_cast<u32x4*>(&pj[r][c0]) = o;
    }
  }
  __syncthreads();

  const int lane = t & 63, wid = t >> 6;
  const int wrow = wid >> 1, wcol = wid & 1;
  const int lr_ = lane & 15, lq = lane >> 4;
  f32x4 acc[4][4];
  #pragma unroll
  for (int a1 = 0; a1 < 4; ++a1)
    #pragma unroll
    for (int a2 = 0; a2 < 4; ++a2) acc[a1][a2] = (f32x4){0.f,0.f,0.f,0.f};
  mfma_k128(pj, wop, wrow, wcol, lr_, lq, acc);

  // epilogue: out = Z_raw + g*(ab + bias)
  #pragma unroll
  for (int fi = 0; fi < 4; ++fi){
    #pragma unroll
    for (int e = 0; e < 4; ++e){
      const int jr = j0 + wrow*64 + fi*16 + lq*4 + e;
      const size_t rowoff = ((size_t)i*NSEQ + jr)*DDIM;
      #pragma unroll
      for (int fj = 0; fj < 4; ++fj){
        const int dd = wcol*64 + fj*16 + lr_;
        const size_t off = rowoff + dd;
        float ab = acc[fi][fj][e] + obias[dd];
        out[off] = Zraw[off] + bf2f(g_ws[off]) * ab;
      }
    }
  }
}

extern "C" void kernel_launch(void* const* d_in, const int* in_sizes, int n_in,
                              void* d_out, int out_size, void* d_ws, size_t ws_size,
                              hipStream_t stream) {
  const float* Zraw  = (const float*)d_in[0];
  const float* mask  = (const float*)d_in[1];
  const float* ln1g  = (const float*)d_in[2];
  const float* ln1b  = (const float*)d_in[3];
  const float* Wlr   = (const float*)d_in[4];
  const float* blr   = (const float*)d_in[5];
  const float* Wgate = (const float*)d_in[6];
  const float* bgate = (const float*)d_in[7];
  const float* Wog   = (const float*)d_in[8];
  const float* bog   = (const float*)d_in[9];
  const float* ln2g  = (const float*)d_in[10];
  const float* ln2b  = (const float*)d_in[11];
  const float* Wop   = (const float*)d_in[12];
  const float* obias = (const float*)d_in[13];
  float* out = (float*)d_out;

  // workspace layout (bf16 = ushort), total ~268.6 MB
  unsigned short* wt      = (unsigned short*)d_ws;          // 768*128
  unsigned short* left_t  = wt + 768*128;                   // [c][pos]
  unsigned short* right_t = left_t + (size_t)DDIM*NPOS;
  unsigned short* g_ws    = right_t + (size_t)DDIM*NPOS;    // [pos][d]
  unsigned short* p_ws    = g_ws + (size_t)DDIM*NPOS;       // [c][i][j]

  k_prep<<<384, 256, 0, stream>>>(Wlr, Wgate, Wog, Wop, wt);
  k1<<<NPOS/128, 256, 0, stream>>>(Zraw, mask, ln1g, ln1b, blr, bgate, bog,
                                   wt, left_t, right_t, g_ws);
  k2<<<dim3(4, 128), 512, 0, stream>>>(left_t, right_t, p_ws);
  k3<<<NPOS/128, 256, 0, stream>>>(p_ws, g_ws, Zraw, ln2g, ln2b, wt, obias, out);
}